// Round 3
// baseline (1312.941 us; speedup 1.0000x reference)
//
#include <hip/hip_runtime.h>
#include <hip/hip_bf16.h>

// ---------------- problem constants ----------------
#define B_  16
#define S_  5
#define W_  12
#define NL_ 49
#define H_  1024
#define V_  15000
#define SEQ_N   14400000          // B*S*W*V
#define STOP_N  80
#define OUT_STOP (SEQ_N)
#define OUT_SCORE (SEQ_N + STOP_N)

typedef __attribute__((ext_vector_type(8))) short     short8;
typedef __attribute__((ext_vector_type(4))) float     f32x4;
typedef __attribute__((ext_vector_type(4))) unsigned int u32x4;
typedef __attribute__((ext_vector_type(4))) unsigned short us4;

// ---------------- ws layout (bytes) ----------------
#define OFF_FCWT   0ull            // 15000x1024 bf16
#define OFF_WWHHP  30720000ull     // 4096x1024 bf16 (gate-permuted)
#define OFF_WWIHP  39108608ull     // 4096x1024 bf16 (gate-permuted)
#define OFF_WSCATP 47497216ull     // 4096x2048 bf16 (gate-permuted, wih|whh)
#define OFF_W1AT   64274432ull     // 1024x1024 bf16
#define OFF_W1BT   66371584ull     // 1024x1024 bf16
#define OFF_FBF    68468736ull     // 784x1024 bf16
#define OFF_XIN    70074368ull     // 960x1024 bf16
#define OFF_PF     72040448ull     // 784x1024 f32
#define OFF_XW     75251712ull     // 960x4096 f32 (cols gate-permuted)
#define OFF_HBALL  90980352ull     // 960x1024 bf16
#define OFF_HWBF0  92946432ull     // 80x1024 bf16
#define OFF_HWBF1  93110272ull     // 80x1024 bf16
#define OFF_ACAT1  93274112ull     // 16x2048 bf16
#define OFF_H      93339648ull     // 16x1024 f32
#define OFF_EVAL   93405184ull     // 784 f32 (pad to 64)
#define OFF_ACAT0  93408384ull     // 16x2048 bf16   -- zero region start
#define OFF_C      93473920ull     // 16x1024 f32
#define OFF_CW     93539456ull     // 80x1024 f32
#define OFF_HPROJ  93867136ull     // 16x1024 f32
#define WS_TOTAL   93932672ull
#define ZERO_BASE  OFF_ACAT0
#define ZERO_BYTES (524288ull)

// ---------------- helpers ----------------
__device__ __forceinline__ unsigned short f2bf(float x){
  unsigned u = __float_as_uint(x);
  u += 0x7fffu + ((u >> 16) & 1u);
  return (unsigned short)(u >> 16);
}
__device__ __forceinline__ float sigm(float x){ return 1.f/(1.f+expf(-x)); }

// ---------------- converts ----------------
__global__ void k_cvt(const float* __restrict__ src, unsigned short* __restrict__ dst, int n){
  int idx = (blockIdx.x*256 + threadIdx.x)*4;
  if (idx >= n) return;
  f32x4 v = *(const f32x4*)(src + idx);
  us4 o; o[0]=f2bf(v[0]); o[1]=f2bf(v[1]); o[2]=f2bf(v[2]); o[3]=f2bf(v[3]);
  *(us4*)(dst + idx) = o;
}

// gate-permuted convert: dst row n <- src row (gate*1024+j), gate=(n>>4)&3, j=((n>>6)<<4)|(n&15)
// src rows are length-1024 f32; dst row stride dld with column offset doff
__global__ void k_cvt_gate(const float* __restrict__ src, unsigned short* __restrict__ dst,
                           int dld, int doff){
  int idx = (blockIdx.x*256 + threadIdx.x)*4;   // over 4096*1024
  int n = idx >> 10, cc = idx & 1023;
  int gate = (n >> 4) & 3, j = ((n >> 6) << 4) | (n & 15);
  f32x4 v = *(const f32x4*)(src + ((size_t)(gate*1024 + j) << 10) + cc);
  us4 o; o[0]=f2bf(v[0]); o[1]=f2bf(v[1]); o[2]=f2bf(v[2]); o[3]=f2bf(v[3]);
  *(us4*)(dst + (size_t)n*dld + doff + cc) = o;
}

// dst[c*dld + r] = bf16(src[(r0+r)*sld + c])
__global__ void k_transp(const float* __restrict__ src, int sld, int r0, int R, int Cc,
                         unsigned short* __restrict__ dst, int dld){
  __shared__ float t[32][33];
  int rb = blockIdx.x*32, cb = blockIdx.y*32;
  int tx = threadIdx.x & 31, ty = threadIdx.x >> 5;
  for (int i = ty; i < 32; i += 8){
    int r = rb + i, c = cb + tx;
    t[i][tx] = (r < R && c < Cc) ? src[(size_t)(r0 + r)*sld + c] : 0.f;
  }
  __syncthreads();
  for (int i = ty; i < 32; i += 8){
    int c = cb + i, r = rb + tx;
    if (c < Cc && r < R) dst[(size_t)c*dld + r] = f2bf(t[tx][i]);
  }
}

// gather word-LSTM inputs: row m=(w*80+s*16+b) -> emb[tok]
__global__ void k_gather(const float* __restrict__ emb, const int* __restrict__ reports,
                         unsigned short* __restrict__ Xin){
  int m = blockIdx.x;
  int w = m / 80, r = m % 80, s = r >> 4, b = r & 15;
  int tok = (w == 0) ? 1 : reports[b*60 + s*12 + (w-1)];
  const float* src = emb + ((size_t)tok << 10);
  int k = threadIdx.x * 4;
  f32x4 v = *(const f32x4*)(src + k);
  us4 o; o[0]=f2bf(v[0]); o[1]=f2bf(v[1]); o[2]=f2bf(v[2]); o[3]=f2bf(v[3]);
  *(us4*)(Xin + (size_t)m*1024 + k) = o;
}

// ---------------- generic bf16 MFMA GEMM (XOR-swizzled LDS) ----------------
// A [M,K] bf16 row-major (lda); Bt [N,K] bf16 row-major (ldb); C f32.
// EPI: 0 plain, 1 +bias, 2 +bias & scatter rows to seq output
template<int BM,int BN,int BK,int WM,int WN,int EPI>
__global__ void k_gemm(const unsigned short* __restrict__ A, int lda,
                       const unsigned short* __restrict__ Bt, int ldb,
                       float* __restrict__ C, int ldc,
                       const float* __restrict__ bias,
                       int M, int N, int K)
{
  constexpr int NT = WM*WN*64;
  constexpr int CH = BK/8;
  __shared__ unsigned short As[BM*BK];
  __shared__ unsigned short Bs[BN*BK];
  const int tid  = threadIdx.x;
  const int lane = tid & 63;
  const int wave = tid >> 6;
  constexpr int WROWS = BM/WM, WCOLS = BN/WN;
  constexpr int FM = WROWS/16, FN = WCOLS/16;
  const int wm = wave / WN, wn = wave % WN;
  const int m0 = blockIdx.x * BM, n0 = blockIdx.y * BN;
  const int g = lane >> 4, fr = lane & 15;
  const int sx = fr & 7;

  f32x4 acc[FM][FN];
  #pragma unroll
  for (int a=0;a<FM;a++)
    #pragma unroll
    for (int b=0;b<FN;b++) acc[a][b] = (f32x4){0.f,0.f,0.f,0.f};

  for (int k0 = 0; k0 < K; k0 += BK) {
    if (k0) __syncthreads();
    for (int i = tid; i < BM*CH; i += NT) {
      int r = i / CH, cb = i % CH;
      int gr = m0 + r; gr = gr < M ? gr : M-1;
      *(u32x4*)(As + r*BK + ((cb ^ (r&7))*8)) = *(const u32x4*)(A + (size_t)gr*lda + k0 + cb*8);
    }
    for (int i = tid; i < BN*CH; i += NT) {
      int r = i / CH, cb = i % CH;
      int gr = n0 + r; gr = gr < N ? gr : N-1;
      *(u32x4*)(Bs + r*BK + ((cb ^ (r&7))*8)) = *(const u32x4*)(Bt + (size_t)gr*ldb + k0 + cb*8);
    }
    __syncthreads();
    #pragma unroll
    for (int kk = 0; kk < BK; kk += 32) {
      const int so = ((kk/8 + g) ^ sx) * 8;
      short8 af[FM], bt[FN];
      #pragma unroll
      for (int fm=0; fm<FM; fm++)
        af[fm] = *(const short8*)(As + (wm*WROWS + fm*16 + fr)*BK + so);
      #pragma unroll
      for (int fn=0; fn<FN; fn++)
        bt[fn] = *(const short8*)(Bs + (wn*WCOLS + fn*16 + fr)*BK + so);
      #pragma unroll
      for (int fm=0; fm<FM; fm++)
        #pragma unroll
        for (int fn=0; fn<FN; fn++)
          acc[fm][fn] = __builtin_amdgcn_mfma_f32_16x16x32_bf16(af[fm], bt[fn], acc[fm][fn], 0, 0, 0);
    }
  }

  #pragma unroll
  for (int fm=0; fm<FM; fm++)
    #pragma unroll
    for (int fn=0; fn<FN; fn++)
      #pragma unroll
      for (int j=0; j<4; j++){
        int m = m0 + wm*WROWS + fm*16 + g*4 + j;
        int n = n0 + wn*WCOLS + fn*16 + fr;
        if (m < M && n < N) {
          float v = acc[fm][fn][j];
          if (EPI >= 1) v += bias[n];
          if (EPI == 2) {
            int b = m & 15, s = (m >> 4) % 5, w = m / 80;
            C[(size_t)((b*5 + s)*12 + w)*V_ + n] = v;
          } else {
            C[(size_t)m*ldc + n] = v;
          }
        }
      }
}

// ---------------- gate GEMM fused with LSTM cell ----------------
// A [M,K] bf16 (lda); Bt = gate-permuted weights [4096,K] (ldb).
// Per thread: fn=0..3 are gates i,f,g,o of unit j. SENT=1: sentence variant.
// h1: primary bf16 h output (row stride ldh1); h2: secondary bf16 (stride 1024);
// hf: f32 h output (SENT only). Xg: precomputed input gates (word only, cols permuted).
template<int BM,int BN,int BK,int WN,int SENT>
__global__ void k_gemm_cell(const unsigned short* __restrict__ A, int lda,
                            const unsigned short* __restrict__ Bt, int ldb,
                            const float* __restrict__ Xg, int ldx,
                            const float* __restrict__ bih, const float* __restrict__ bhh,
                            float* __restrict__ cst,
                            unsigned short* __restrict__ h1, int ldh1,
                            unsigned short* __restrict__ h2,
                            float* __restrict__ hf,
                            int M, int K)
{
  constexpr int NT = WN*64;
  constexpr int CH = BK/8;
  __shared__ unsigned short As[BM*BK];
  __shared__ unsigned short Bs[BN*BK];
  const int tid  = threadIdx.x;
  const int lane = tid & 63;
  const int wn   = tid >> 6;          // wave = n-slice (WM=1)
  const int m0 = blockIdx.x * BM, n0 = blockIdx.y * BN;
  const int g = lane >> 4, fr = lane & 15;
  const int sx = fr & 7;

  f32x4 acc[4];
  #pragma unroll
  for (int b=0;b<4;b++) acc[b] = (f32x4){0.f,0.f,0.f,0.f};

  for (int k0 = 0; k0 < K; k0 += BK) {
    if (k0) __syncthreads();
    for (int i = tid; i < BM*CH; i += NT) {
      int r = i / CH, cb = i % CH;
      int gr = m0 + r; gr = gr < M ? gr : M-1;
      *(u32x4*)(As + r*BK + ((cb ^ (r&7))*8)) = *(const u32x4*)(A + (size_t)gr*lda + k0 + cb*8);
    }
    for (int i = tid; i < BN*CH; i += NT) {
      int r = i / CH, cb = i % CH;
      *(u32x4*)(Bs + r*BK + ((cb ^ (r&7))*8)) = *(const u32x4*)(Bt + (size_t)(n0 + r)*ldb + k0 + cb*8);
    }
    __syncthreads();
    #pragma unroll
    for (int kk = 0; kk < BK; kk += 32) {
      const int so = ((kk/8 + g) ^ sx) * 8;
      short8 af = *(const short8*)(As + fr*BK + so);
      #pragma unroll
      for (int fn=0; fn<4; fn++){
        short8 bt = *(const short8*)(Bs + (wn*64 + fn*16 + fr)*BK + so);
        acc[fn] = __builtin_amdgcn_mfma_f32_16x16x32_bf16(af, bt, acc[fn], 0, 0, 0);
      }
    }
  }

  const int nb = n0 + wn*64 + fr;       // column of gate 0
  const int j  = ((n0 + wn*64) >> 2) + fr;
  const float b0 = bih[j]        + bhh[j];
  const float b1 = bih[1024 + j] + bhh[1024 + j];
  const float b2 = bih[2048 + j] + bhh[2048 + j];
  const float b3 = bih[3072 + j] + bhh[3072 + j];
  #pragma unroll
  for (int jj=0; jj<4; jj++){
    int m = m0 + g*4 + jj;
    if (m < M){
      float gi = acc[0][jj] + b0;
      float gf = acc[1][jj] + b1;
      float gg = acc[2][jj] + b2;
      float go = acc[3][jj] + b3;
      if (!SENT){
        const float* xg = Xg + (size_t)m*ldx + nb;
        gi += xg[0]; gf += xg[16]; gg += xg[32]; go += xg[48];
      }
      float cn = sigm(gf)*cst[m*1024 + j] + sigm(gi)*tanhf(gg);
      float hn = sigm(go)*tanhf(cn);
      cst[m*1024 + j] = cn;
      unsigned short hb = f2bf(hn);
      h1[(size_t)m*ldh1 + j] = hb;
      h2[(size_t)m*1024 + j] = hb;
      if (SENT) hf[m*1024 + j] = hn;
    }
  }
}

// ---------------- attention ----------------
// evals[b*49+n] = sum_k tanh(PF[b,n,k] + hproj[b,k]) * w2[k]; 784 blocks
__global__ void k_attn_e(const float* __restrict__ PF, const float* __restrict__ hproj,
                         const float* __restrict__ w2, float* __restrict__ evals)
{
  const int bn = blockIdx.x;
  const int b  = bn / NL_;
  const int tid = threadIdx.x;
  __shared__ float red[4];
  const float* pf = PF + ((size_t)bn << 10);
  const float* hp = hproj + (b << 10);
  int k = tid * 4;
  f32x4 a = *(const f32x4*)(pf + k);
  f32x4 hh = *(const f32x4*)(hp + k);
  f32x4 w = *(const f32x4*)(w2 + k);
  float p = tanhf(a[0]+hh[0])*w[0] + tanhf(a[1]+hh[1])*w[1]
          + tanhf(a[2]+hh[2])*w[2] + tanhf(a[3]+hh[3])*w[3];
  #pragma unroll
  for (int o = 32; o; o >>= 1) p += __shfl_down(p, o, 64);
  if ((tid & 63) == 0) red[tid >> 6] = p;
  __syncthreads();
  if (tid == 0) evals[bn] = red[0] + red[1] + red[2] + red[3];
}

// softmax over 49, weighted feature sum, optional scores/stop; 16 blocks
template<int INIT>
__global__ void k_attn_fin(const float* __restrict__ evals, const float* __restrict__ features,
                           const float* __restrict__ h, const float* __restrict__ stop_w,
                           const float* __restrict__ stop_b,
                           unsigned short* __restrict__ Acat, float* __restrict__ outp, int s)
{
  const int b = blockIdx.x, tid = threadIdx.x;
  __shared__ float scs[64];
  __shared__ float red[4];
  if (tid < 64){
    float e = (tid < NL_) ? evals[b*NL_ + tid] : -1e30f;
    float mx = e;
    #pragma unroll
    for (int o = 32; o; o >>= 1) mx = fmaxf(mx, __shfl_xor(mx, o, 64));
    float ex = (tid < NL_) ? expf(e - mx) : 0.f;
    float dn = ex;
    #pragma unroll
    for (int o = 32; o; o >>= 1) dn += __shfl_xor(dn, o, 64);
    float sc = ex / dn;
    if (tid < NL_){
      scs[tid] = sc;
      if (!INIT) outp[OUT_SCORE + (b*5 + s)*NL_ + tid] = sc;
    }
  }
  __syncthreads();
  {
    int f0 = tid * 4;
    f32x4 a = (f32x4){0.f,0.f,0.f,0.f};
    const float* fb = features + (((size_t)b*NL_) << 10) + f0;
    #pragma unroll 7
    for (int n = 0; n < NL_; n++){
      f32x4 v = *(const f32x4*)(fb + ((size_t)n << 10));
      float sc = scs[n];
      a[0] += sc*v[0]; a[1] += sc*v[1]; a[2] += sc*v[2]; a[3] += sc*v[3];
    }
    us4 o4; o4[0]=f2bf(a[0]); o4[1]=f2bf(a[1]); o4[2]=f2bf(a[2]); o4[3]=f2bf(a[3]);
    *(us4*)(Acat + b*2048 + f0) = o4;
  }
  if (!INIT){
    int k = tid * 4;
    f32x4 hv = *(const f32x4*)(h + (b << 10) + k);
    f32x4 sw = *(const f32x4*)(stop_w + k);
    float p = hv[0]*sw[0] + hv[1]*sw[1] + hv[2]*sw[2] + hv[3]*sw[3];
    #pragma unroll
    for (int o = 32; o; o >>= 1) p += __shfl_down(p, o, 64);
    if ((tid & 63) == 0) red[tid >> 6] = p;
    __syncthreads();
    if (tid == 0) outp[OUT_STOP + b*5 + s] = sigm(red[0]+red[1]+red[2]+red[3] + stop_b[0]);
  }
}

// ---------------- host ----------------
extern "C" void kernel_launch(void* const* d_in, const int* in_sizes, int n_in,
                              void* d_out, int out_size, void* d_ws, size_t ws_size,
                              hipStream_t stream)
{
  const float* features = (const float*)d_in[0];
  const int*   reports  = (const int*)d_in[1];
  const float* attn_w1  = (const float*)d_in[2];
  const float* attn_b1  = (const float*)d_in[3];
  const float* attn_w2  = (const float*)d_in[4];
  const float* s_wih    = (const float*)d_in[6];
  const float* s_whh    = (const float*)d_in[7];
  const float* s_bih    = (const float*)d_in[8];
  const float* s_bhh    = (const float*)d_in[9];
  const float* stop_w   = (const float*)d_in[10];
  const float* stop_b   = (const float*)d_in[11];
  const float* emb      = (const float*)d_in[12];
  const float* w_wih    = (const float*)d_in[13];
  const float* w_whh    = (const float*)d_in[14];
  const float* w_bih    = (const float*)d_in[15];
  const float* w_bhh    = (const float*)d_in[16];
  const float* fc_w     = (const float*)d_in[17];
  const float* fc_b     = (const float*)d_in[18];
  float* out = (float*)d_out;
  char*  ws  = (char*)d_ws;
  if (ws_size < WS_TOTAL) return;

  unsigned short* FCWT   = (unsigned short*)(ws + OFF_FCWT);
  unsigned short* WWHHP  = (unsigned short*)(ws + OFF_WWHHP);
  unsigned short* WWIHP  = (unsigned short*)(ws + OFF_WWIHP);
  unsigned short* WSCATP = (unsigned short*)(ws + OFF_WSCATP);
  unsigned short* W1AT   = (unsigned short*)(ws + OFF_W1AT);
  unsigned short* W1BT   = (unsigned short*)(ws + OFF_W1BT);
  unsigned short* FBF    = (unsigned short*)(ws + OFF_FBF);
  unsigned short* XIN    = (unsigned short*)(ws + OFF_XIN);
  float*          PF     = (float*)(ws + OFF_PF);
  float*          XW     = (float*)(ws + OFF_XW);
  unsigned short* HBALL  = (unsigned short*)(ws + OFF_HBALL);
  unsigned short* HW0    = (unsigned short*)(ws + OFF_HWBF0);
  unsigned short* HW1    = (unsigned short*)(ws + OFF_HWBF1);
  unsigned short* ACAT0  = (unsigned short*)(ws + OFF_ACAT0);
  unsigned short* ACAT1  = (unsigned short*)(ws + OFF_ACAT1);
  float*          Hst    = (float*)(ws + OFF_H);
  float*          Cst    = (float*)(ws + OFF_C);
  float*          CW     = (float*)(ws + OFF_CW);
  float*          HPROJ  = (float*)(ws + OFF_HPROJ);
  float*          EVAL   = (float*)(ws + OFF_EVAL);

  hipMemsetAsync(ws + ZERO_BASE, 0, ZERO_BYTES, stream);

  // weight prep
  k_cvt<<<784, 256, 0, stream>>>(features, FBF, 802816);
  k_cvt_gate<<<4096, 256, 0, stream>>>(w_whh, WWHHP, 1024, 0);
  k_cvt_gate<<<4096, 256, 0, stream>>>(w_wih, WWIHP, 1024, 0);
  k_cvt_gate<<<4096, 256, 0, stream>>>(s_wih, WSCATP, 2048, 0);
  k_cvt_gate<<<4096, 256, 0, stream>>>(s_whh, WSCATP, 2048, 1024);
  k_transp<<<dim3(32,32),  256, 0, stream>>>(attn_w1, 1024, 0,    1024, 1024,  W1AT, 1024);
  k_transp<<<dim3(32,32),  256, 0, stream>>>(attn_w1, 1024, 1024, 1024, 1024,  W1BT, 1024);
  k_transp<<<dim3(32,469), 256, 0, stream>>>(fc_w,   15000, 0,    1024, 15000, FCWT, 1024);
  k_gather<<<960, 256, 0, stream>>>(emb, reports, XIN);

  // PF = features @ w1[:F] + b1   (784,1024,1024)
  k_gemm<64,64,128,2,2,1><<<dim3(13,16), 256, 0, stream>>>(FBF,1024, W1AT,1024, PF,1024, attn_b1, 784,1024,1024);
  // XW = Xin @ w_wih^T (permuted cols)  (960,4096,1024)
  k_gemm<64,128,128,2,2,0><<<dim3(15,32), 256, 0, stream>>>(XIN,1024, WWIHP,1024, XW,4096, nullptr, 960,4096,1024);

  // att0 (h=0: HPROJ zeroed)
  k_attn_e<<<784, 256, 0, stream>>>(PF, HPROJ, attn_w2, EVAL);
  k_attn_fin<1><<<16, 256, 0, stream>>>(EVAL, features, Hst, stop_w, stop_b, ACAT0, out, 0);

  // sentence chain (fused gate GEMM + cell)
  unsigned short* ACS[2] = {ACAT0, ACAT1};
  for (int s = 0; s < S_; s++){
    unsigned short* cur = ACS[s & 1];
    unsigned short* nxt = ACS[(s + 1) & 1];
    k_gemm_cell<16,128,128,2,1><<<dim3(1,32), 128, 0, stream>>>(
        cur, 2048, WSCATP, 2048, nullptr, 0, s_bih, s_bhh, Cst,
        nxt + 1024, 2048, HW0 + s*16*1024, Hst, 16, 2048);
    k_gemm<16,64,256,1,4,0><<<dim3(1,16), 256, 0, stream>>>(
        nxt + 1024, 2048, W1BT, 1024, HPROJ, 1024, nullptr, 16, 1024, 1024);
    k_attn_e<<<784, 256, 0, stream>>>(PF, HPROJ, attn_w2, EVAL);
    k_attn_fin<0><<<16, 256, 0, stream>>>(EVAL, features, Hst, stop_w, stop_b, nxt, out, s);
  }

  // word chain (batched over 5 sentences; double-buffered h)
  unsigned short* HW[2] = {HW0, HW1};
  for (int w = 0; w < W_; w++){
    k_gemm_cell<16,128,128,2,0><<<dim3(5,32), 128, 0, stream>>>(
        HW[w & 1], 1024, WWHHP, 1024, XW + (size_t)w*80*4096, 4096, w_bih, w_bhh, CW,
        HW[(w + 1) & 1], 1024, HBALL + (size_t)w*80*1024, nullptr, 80, 1024);
  }

  // fc: preds = Hball @ fc_w + fc_b, scattered into seq layout
  k_gemm<128,128,64,2,2,2><<<dim3(8,118), 256, 0, stream>>>(HBALL,1024, FCWT,1024, out,V_, fc_b, 960,15000,1024);
}

// Round 4
// 559.054 us; speedup vs baseline: 2.3485x; 2.3485x over previous
//
#include <hip/hip_runtime.h>
#include <hip/hip_bf16.h>

// ---------------- problem constants ----------------
#define B_  16
#define S_  5
#define W_  12
#define NL_ 49
#define H_  1024
#define V_  15000
#define SEQ_N   14400000          // B*S*W*V
#define STOP_N  80
#define OUT_STOP (SEQ_N)
#define OUT_SCORE (SEQ_N + STOP_N)

typedef __attribute__((ext_vector_type(8))) short     short8;
typedef __attribute__((ext_vector_type(4))) float     f32x4;
typedef __attribute__((ext_vector_type(4))) unsigned int u32x4;
typedef __attribute__((ext_vector_type(4))) unsigned short us4;

// ---------------- ws layout (bytes) ----------------
#define OFF_FCWT   0ull            // 15000x1024 bf16
#define OFF_WWHHP  30720000ull     // 4096x1024 bf16 (gate-permuted)
#define OFF_WWIHP  39108608ull     // 4096x1024 bf16 (gate-permuted)
#define OFF_WSCATP 47497216ull     // 4096x2048 bf16 (gate-permuted, wih|whh)
#define OFF_W1AT   64274432ull     // 1024x1024 bf16
#define OFF_W1BT   66371584ull     // 1024x1024 bf16
#define OFF_FBF    68468736ull     // 784x1024 bf16
#define OFF_XIN    70074368ull     // 960x1024 bf16
#define OFF_PF     72040448ull     // 784x1024 f32
#define OFF_XW     75251712ull     // 960x4096 f32 (cols gate-permuted)
#define OFF_HBALL  90980352ull     // 960x1024 bf16
#define OFF_HWBF0  92946432ull     // 80x1024 bf16
#define OFF_HWBF1  93110272ull     // 80x1024 bf16
#define OFF_ACAT1  93274112ull     // 16x2048 bf16
#define OFF_H      93339648ull     // 16x1024 f32
#define OFF_EVAL   93405184ull     // 784 f32 (pad to 800)
#define OFF_ACAT0  93408384ull     // 16x2048 bf16   -- zero region start
#define OFF_C      93473920ull     // 16x1024 f32
#define OFF_CW     93539456ull     // 80x1024 f32
#define OFF_HPROJ  93867136ull     // 16x1024 f32
#define WS_TOTAL   93932672ull
#define ZERO_BASE  OFF_ACAT0
#define ZERO_BYTES (524288ull)

// ---------------- helpers ----------------
__device__ __forceinline__ unsigned short f2bf(float x){
  unsigned u = __float_as_uint(x);
  u += 0x7fffu + ((u >> 16) & 1u);
  return (unsigned short)(u >> 16);
}
__device__ __forceinline__ float sigm(float x){ return 1.f/(1.f+expf(-x)); }

typedef __attribute__((address_space(3))) unsigned int  as3_u32;
typedef __attribute__((address_space(1))) const unsigned int as1_u32;

__device__ __forceinline__ void gl16(const void* g, void* l){
  __builtin_amdgcn_global_load_lds((as1_u32*)g, (as3_u32*)l, 16, 0, 0);
}

// Stage ROWS x (CH*8) bf16 tile into LDS via global_load_lds, with XOR-swizzled
// per-lane SOURCE so LDS slot [r][cb'] holds global chunk cb'^(r&7).
// gbase already offset to k0; grs = global row stride (elements); rows clamped to rmax.
template<int ROWS,int CH,int NW>
__device__ __forceinline__ void stage_swz(const unsigned short* __restrict__ gbase, int grs,
                                          unsigned short* lds, int wid, int lane,
                                          int r0, int rmax){
  constexpr int RPI = 64/CH;          // rows per issue (64 lanes x 16B)
  constexpr int NISS = ROWS/RPI;
  const int r_in = lane / CH;
  const int cbp  = lane % CH;
  #pragma unroll
  for (int it = wid; it < NISS; it += NW){
    int rl = it*RPI + r_in;
    int gr = r0 + rl; gr = gr < rmax ? gr : rmax-1;
    int cb = cbp ^ (rl & 7);
    gl16(gbase + (size_t)gr*grs + cb*8, lds + it*RPI*CH*8);
  }
}

// ---------------- converts ----------------
__global__ void k_cvt(const float* __restrict__ src, unsigned short* __restrict__ dst, int n){
  int idx = (blockIdx.x*256 + threadIdx.x)*4;
  if (idx >= n) return;
  f32x4 v = *(const f32x4*)(src + idx);
  us4 o; o[0]=f2bf(v[0]); o[1]=f2bf(v[1]); o[2]=f2bf(v[2]); o[3]=f2bf(v[3]);
  *(us4*)(dst + idx) = o;
}

// gate-permuted convert: dst row n <- src row (gate*1024+j), gate=(n>>4)&3, j=((n>>6)<<4)|(n&15)
__global__ void k_cvt_gate(const float* __restrict__ src, unsigned short* __restrict__ dst,
                           int dld, int doff){
  int idx = (blockIdx.x*256 + threadIdx.x)*4;   // over 4096*1024
  int n = idx >> 10, cc = idx & 1023;
  int gate = (n >> 4) & 3, j = ((n >> 6) << 4) | (n & 15);
  f32x4 v = *(const f32x4*)(src + ((size_t)(gate*1024 + j) << 10) + cc);
  us4 o; o[0]=f2bf(v[0]); o[1]=f2bf(v[1]); o[2]=f2bf(v[2]); o[3]=f2bf(v[3]);
  *(us4*)(dst + (size_t)n*dld + doff + cc) = o;
}

// dst[c*dld + r] = bf16(src[(r0+r)*sld + c])
__global__ void k_transp(const float* __restrict__ src, int sld, int r0, int R, int Cc,
                         unsigned short* __restrict__ dst, int dld){
  __shared__ float t[32][33];
  int rb = blockIdx.x*32, cb = blockIdx.y*32;
  int tx = threadIdx.x & 31, ty = threadIdx.x >> 5;
  for (int i = ty; i < 32; i += 8){
    int r = rb + i, c = cb + tx;
    t[i][tx] = (r < R && c < Cc) ? src[(size_t)(r0 + r)*sld + c] : 0.f;
  }
  __syncthreads();
  for (int i = ty; i < 32; i += 8){
    int c = cb + i, r = rb + tx;
    if (c < Cc && r < R) dst[(size_t)c*dld + r] = f2bf(t[tx][i]);
  }
}

// gather word-LSTM inputs: row m=(w*80+s*16+b) -> emb[tok]
__global__ void k_gather(const float* __restrict__ emb, const int* __restrict__ reports,
                         unsigned short* __restrict__ Xin){
  int m = blockIdx.x;
  int w = m / 80, r = m % 80, s = r >> 4, b = r & 15;
  int tok = (w == 0) ? 1 : reports[b*60 + s*12 + (w-1)];
  const float* src = emb + ((size_t)tok << 10);
  int k = threadIdx.x * 4;
  f32x4 v = *(const f32x4*)(src + k);
  us4 o; o[0]=f2bf(v[0]); o[1]=f2bf(v[1]); o[2]=f2bf(v[2]); o[3]=f2bf(v[3]);
  *(us4*)(Xin + (size_t)m*1024 + k) = o;
}

// ---------------- generic bf16 MFMA GEMM (gl_lds + XOR-swizzled LDS) ----------------
// n-major grid: n0 = blockIdx.x*BN, m0 = blockIdx.y*BM.
// EPI: 0 plain, 1 +bias, 2 +bias & scatter rows to seq output (nt), 3 plain nt
template<int BM,int BN,int BK,int WM,int WN,int EPI>
__global__ void k_gemm(const unsigned short* __restrict__ A, int lda,
                       const unsigned short* __restrict__ Bt, int ldb,
                       float* __restrict__ C, int ldc,
                       const float* __restrict__ bias,
                       int M, int N, int K)
{
  constexpr int NWV = WM*WN;
  constexpr int CH = BK/8;
  __shared__ __align__(16) unsigned short As[BM*BK];
  __shared__ __align__(16) unsigned short Bs[BN*BK];
  const int n0 = blockIdx.x * BN, m0 = blockIdx.y * BM;
  if (n0 >= N) return;
  const int tid  = threadIdx.x;
  const int lane = tid & 63;
  const int wave = tid >> 6;
  constexpr int WROWS = BM/WM, WCOLS = BN/WN;
  constexpr int FM = WROWS/16, FN = WCOLS/16;
  const int wm = wave / WN, wn = wave % WN;
  const int g = lane >> 4, fr = lane & 15;
  const int sx = fr & 7;

  f32x4 acc[FM][FN];
  #pragma unroll
  for (int a=0;a<FM;a++)
    #pragma unroll
    for (int b=0;b<FN;b++) acc[a][b] = (f32x4){0.f,0.f,0.f,0.f};

  for (int k0 = 0; k0 < K; k0 += BK) {
    if (k0) __syncthreads();
    stage_swz<BM,CH,NWV>(A + k0, lda, As, wave, lane, m0, M);
    stage_swz<BN,CH,NWV>(Bt + k0, ldb, Bs, wave, lane, n0, N);
    __syncthreads();
    #pragma unroll
    for (int kk = 0; kk < BK; kk += 32) {
      const int so = ((kk/8 + g) ^ sx) * 8;
      short8 af[FM], bt[FN];
      #pragma unroll
      for (int fm=0; fm<FM; fm++)
        af[fm] = *(const short8*)(As + (wm*WROWS + fm*16 + fr)*BK + so);
      #pragma unroll
      for (int fn=0; fn<FN; fn++)
        bt[fn] = *(const short8*)(Bs + (wn*WCOLS + fn*16 + fr)*BK + so);
      #pragma unroll
      for (int fm=0; fm<FM; fm++)
        #pragma unroll
        for (int fn=0; fn<FN; fn++)
          acc[fm][fn] = __builtin_amdgcn_mfma_f32_16x16x32_bf16(af[fm], bt[fn], acc[fm][fn], 0, 0, 0);
    }
  }

  #pragma unroll
  for (int fm=0; fm<FM; fm++)
    #pragma unroll
    for (int fn=0; fn<FN; fn++)
      #pragma unroll
      for (int j=0; j<4; j++){
        int m = m0 + wm*WROWS + fm*16 + g*4 + j;
        int n = n0 + wn*WCOLS + fn*16 + fr;
        if (m < M && n < N) {
          float v = acc[fm][fn][j];
          if (EPI == 1 || EPI == 2) v += bias[n];
          if (EPI == 2) {
            int b = m & 15, s = (m >> 4) % 5, w = m / 80;
            __builtin_nontemporal_store(v, &C[(size_t)((b*5 + s)*12 + w)*V_ + n]);
          } else if (EPI == 3) {
            __builtin_nontemporal_store(v, &C[(size_t)m*ldc + n]);
          } else {
            C[(size_t)m*ldc + n] = v;
          }
        }
      }
}

// ---------------- gate GEMM fused with LSTM cell ----------------
// n-major grid: n0 = blockIdx.x*BN, m0 = blockIdx.y*BM. 128 threads (WN=2 waves).
template<int BM,int BN,int BK,int WN,int SENT>
__global__ void k_gemm_cell(const unsigned short* __restrict__ A, int lda,
                            const unsigned short* __restrict__ Bt, int ldb,
                            const float* __restrict__ Xg, int ldx,
                            const float* __restrict__ bih, const float* __restrict__ bhh,
                            float* __restrict__ cst,
                            unsigned short* __restrict__ h1, int ldh1,
                            unsigned short* __restrict__ h2,
                            float* __restrict__ hf,
                            int M, int K)
{
  constexpr int CH = BK/8;
  __shared__ __align__(16) unsigned short As[BM*BK];
  __shared__ __align__(16) unsigned short Bs[BN*BK];
  const int tid  = threadIdx.x;
  const int lane = tid & 63;
  const int wn   = tid >> 6;
  const int n0 = blockIdx.x * BN, m0 = blockIdx.y * BM;
  const int g = lane >> 4, fr = lane & 15;
  const int sx = fr & 7;

  f32x4 acc[4];
  #pragma unroll
  for (int b=0;b<4;b++) acc[b] = (f32x4){0.f,0.f,0.f,0.f};

  for (int k0 = 0; k0 < K; k0 += BK) {
    if (k0) __syncthreads();
    stage_swz<BM,CH,WN>(A + k0, lda, As, wn, lane, m0, M);
    stage_swz<BN,CH,WN>(Bt + k0, ldb, Bs, wn, lane, n0, 4096);
    __syncthreads();
    #pragma unroll
    for (int kk = 0; kk < BK; kk += 32) {
      const int so = ((kk/8 + g) ^ sx) * 8;
      short8 af = *(const short8*)(As + fr*BK + so);
      #pragma unroll
      for (int fn=0; fn<4; fn++){
        short8 bt = *(const short8*)(Bs + (wn*64 + fn*16 + fr)*BK + so);
        acc[fn] = __builtin_amdgcn_mfma_f32_16x16x32_bf16(af, bt, acc[fn], 0, 0, 0);
      }
    }
  }

  const int nb = n0 + wn*64 + fr;       // column of gate 0
  const int j  = ((n0 + wn*64) >> 2) + fr;
  const float b0 = bih[j]        + bhh[j];
  const float b1 = bih[1024 + j] + bhh[1024 + j];
  const float b2 = bih[2048 + j] + bhh[2048 + j];
  const float b3 = bih[3072 + j] + bhh[3072 + j];
  #pragma unroll
  for (int jj=0; jj<4; jj++){
    int m = m0 + g*4 + jj;
    if (m < M){
      float gi = acc[0][jj] + b0;
      float gf = acc[1][jj] + b1;
      float gg = acc[2][jj] + b2;
      float go = acc[3][jj] + b3;
      if (!SENT){
        const float* xg = Xg + (size_t)m*ldx + nb;
        gi += xg[0]; gf += xg[16]; gg += xg[32]; go += xg[48];
      }
      float cn = sigm(gf)*cst[m*1024 + j] + sigm(gi)*tanhf(gg);
      float hn = sigm(go)*tanhf(cn);
      cst[m*1024 + j] = cn;
      unsigned short hb = f2bf(hn);
      h1[(size_t)m*ldh1 + j] = hb;
      h2[(size_t)m*1024 + j] = hb;
      if (SENT) hf[m*1024 + j] = hn;
    }
  }
}

// ---------------- attention ----------------
__global__ void k_attn_e(const float* __restrict__ PF, const float* __restrict__ hproj,
                         const float* __restrict__ w2, float* __restrict__ evals)
{
  const int bn = blockIdx.x;
  const int b  = bn / NL_;
  const int tid = threadIdx.x;
  __shared__ float red[4];
  const float* pf = PF + ((size_t)bn << 10);
  const float* hp = hproj + (b << 10);
  int k = tid * 4;
  f32x4 a = *(const f32x4*)(pf + k);
  f32x4 hh = *(const f32x4*)(hp + k);
  f32x4 w = *(const f32x4*)(w2 + k);
  float p = tanhf(a[0]+hh[0])*w[0] + tanhf(a[1]+hh[1])*w[1]
          + tanhf(a[2]+hh[2])*w[2] + tanhf(a[3]+hh[3])*w[3];
  #pragma unroll
  for (int o = 32; o; o >>= 1) p += __shfl_down(p, o, 64);
  if ((tid & 63) == 0) red[tid >> 6] = p;
  __syncthreads();
  if (tid == 0) evals[bn] = red[0] + red[1] + red[2] + red[3];
}

template<int INIT>
__global__ void k_attn_fin(const float* __restrict__ evals, const float* __restrict__ features,
                           const float* __restrict__ h, const float* __restrict__ stop_w,
                           const float* __restrict__ stop_b,
                           unsigned short* __restrict__ Acat, float* __restrict__ outp, int s)
{
  const int b = blockIdx.x, tid = threadIdx.x;
  __shared__ float scs[64];
  __shared__ float red[4];
  if (tid < 64){
    float e = (tid < NL_) ? evals[b*NL_ + tid] : -1e30f;
    float mx = e;
    #pragma unroll
    for (int o = 32; o; o >>= 1) mx = fmaxf(mx, __shfl_xor(mx, o, 64));
    float ex = (tid < NL_) ? expf(e - mx) : 0.f;
    float dn = ex;
    #pragma unroll
    for (int o = 32; o; o >>= 1) dn += __shfl_xor(dn, o, 64);
    float sc = ex / dn;
    if (tid < NL_){
      scs[tid] = sc;
      if (!INIT) outp[OUT_SCORE + (b*5 + s)*NL_ + tid] = sc;
    }
  }
  __syncthreads();
  {
    int f0 = tid * 4;
    f32x4 a = (f32x4){0.f,0.f,0.f,0.f};
    const float* fb = features + (((size_t)b*NL_) << 10) + f0;
    #pragma unroll 7
    for (int n = 0; n < NL_; n++){
      f32x4 v = *(const f32x4*)(fb + ((size_t)n << 10));
      float sc = scs[n];
      a[0] += sc*v[0]; a[1] += sc*v[1]; a[2] += sc*v[2]; a[3] += sc*v[3];
    }
    us4 o4; o4[0]=f2bf(a[0]); o4[1]=f2bf(a[1]); o4[2]=f2bf(a[2]); o4[3]=f2bf(a[3]);
    *(us4*)(Acat + b*2048 + f0) = o4;
  }
  if (!INIT){
    int k = tid * 4;
    f32x4 hv = *(const f32x4*)(h + (b << 10) + k);
    f32x4 sw = *(const f32x4*)(stop_w + k);
    float p = hv[0]*sw[0] + hv[1]*sw[1] + hv[2]*sw[2] + hv[3]*sw[3];
    #pragma unroll
    for (int o = 32; o; o >>= 1) p += __shfl_down(p, o, 64);
    if ((tid & 63) == 0) red[tid >> 6] = p;
    __syncthreads();
    if (tid == 0) outp[OUT_STOP + b*5 + s] = sigm(red[0]+red[1]+red[2]+red[3] + stop_b[0]);
  }
}

// ---------------- host ----------------
extern "C" void kernel_launch(void* const* d_in, const int* in_sizes, int n_in,
                              void* d_out, int out_size, void* d_ws, size_t ws_size,
                              hipStream_t stream)
{
  const float* features = (const float*)d_in[0];
  const int*   reports  = (const int*)d_in[1];
  const float* attn_w1  = (const float*)d_in[2];
  const float* attn_b1  = (const float*)d_in[3];
  const float* attn_w2  = (const float*)d_in[4];
  const float* s_wih    = (const float*)d_in[6];
  const float* s_whh    = (const float*)d_in[7];
  const float* s_bih    = (const float*)d_in[8];
  const float* s_bhh    = (const float*)d_in[9];
  const float* stop_w   = (const float*)d_in[10];
  const float* stop_b   = (const float*)d_in[11];
  const float* emb      = (const float*)d_in[12];
  const float* w_wih    = (const float*)d_in[13];
  const float* w_whh    = (const float*)d_in[14];
  const float* w_bih    = (const float*)d_in[15];
  const float* w_bhh    = (const float*)d_in[16];
  const float* fc_w     = (const float*)d_in[17];
  const float* fc_b     = (const float*)d_in[18];
  float* out = (float*)d_out;
  char*  ws  = (char*)d_ws;
  if (ws_size < WS_TOTAL) return;

  unsigned short* FCWT   = (unsigned short*)(ws + OFF_FCWT);
  unsigned short* WWHHP  = (unsigned short*)(ws + OFF_WWHHP);
  unsigned short* WWIHP  = (unsigned short*)(ws + OFF_WWIHP);
  unsigned short* WSCATP = (unsigned short*)(ws + OFF_WSCATP);
  unsigned short* W1AT   = (unsigned short*)(ws + OFF_W1AT);
  unsigned short* W1BT   = (unsigned short*)(ws + OFF_W1BT);
  unsigned short* FBF    = (unsigned short*)(ws + OFF_FBF);
  unsigned short* XIN    = (unsigned short*)(ws + OFF_XIN);
  float*          PF     = (float*)(ws + OFF_PF);
  float*          XW     = (float*)(ws + OFF_XW);
  unsigned short* HBALL  = (unsigned short*)(ws + OFF_HBALL);
  unsigned short* HW0    = (unsigned short*)(ws + OFF_HWBF0);
  unsigned short* HW1    = (unsigned short*)(ws + OFF_HWBF1);
  unsigned short* ACAT0  = (unsigned short*)(ws + OFF_ACAT0);
  unsigned short* ACAT1  = (unsigned short*)(ws + OFF_ACAT1);
  float*          Hst    = (float*)(ws + OFF_H);
  float*          Cst    = (float*)(ws + OFF_C);
  float*          CW     = (float*)(ws + OFF_CW);
  float*          HPROJ  = (float*)(ws + OFF_HPROJ);
  float*          EVAL   = (float*)(ws + OFF_EVAL);

  hipMemsetAsync(ws + ZERO_BASE, 0, ZERO_BYTES, stream);

  // weight prep
  k_cvt<<<784, 256, 0, stream>>>(features, FBF, 802816);
  k_cvt_gate<<<4096, 256, 0, stream>>>(w_whh, WWHHP, 1024, 0);
  k_cvt_gate<<<4096, 256, 0, stream>>>(w_wih, WWIHP, 1024, 0);
  k_cvt_gate<<<4096, 256, 0, stream>>>(s_wih, WSCATP, 2048, 0);
  k_cvt_gate<<<4096, 256, 0, stream>>>(s_whh, WSCATP, 2048, 1024);
  k_transp<<<dim3(32,32),  256, 0, stream>>>(attn_w1, 1024, 0,    1024, 1024,  W1AT, 1024);
  k_transp<<<dim3(32,32),  256, 0, stream>>>(attn_w1, 1024, 1024, 1024, 1024,  W1BT, 1024);
  k_transp<<<dim3(32,469), 256, 0, stream>>>(fc_w,   15000, 0,    1024, 15000, FCWT, 1024);
  k_gather<<<960, 256, 0, stream>>>(emb, reports, XIN);

  // PF = features @ w1[:F] + b1   (784,1024,1024)  [n-major grid]
  k_gemm<64,64,128,2,2,1><<<dim3(16,13), 256, 0, stream>>>(FBF,1024, W1AT,1024, PF,1024, attn_b1, 784,1024,1024);
  // XW = Xin @ w_wih^T (permuted cols)  (960,4096,1024), nt-store
  k_gemm<64,128,128,2,2,3><<<dim3(32,15), 256, 0, stream>>>(XIN,1024, WWIHP,1024, XW,4096, nullptr, 960,4096,1024);

  // att0 (h=0: HPROJ zeroed)
  k_attn_e<<<784, 256, 0, stream>>>(PF, HPROJ, attn_w2, EVAL);
  k_attn_fin<1><<<16, 256, 0, stream>>>(EVAL, features, Hst, stop_w, stop_b, ACAT0, out, 0);

  // sentence chain (fused gate GEMM + cell)
  unsigned short* ACS[2] = {ACAT0, ACAT1};
  for (int s = 0; s < S_; s++){
    unsigned short* cur = ACS[s & 1];
    unsigned short* nxt = ACS[(s + 1) & 1];
    k_gemm_cell<16,128,128,2,1><<<dim3(32,1), 128, 0, stream>>>(
        cur, 2048, WSCATP, 2048, nullptr, 0, s_bih, s_bhh, Cst,
        nxt + 1024, 2048, HW0 + s*16*1024, Hst, 16, 2048);
    k_gemm<16,64,256,1,4,0><<<dim3(16,1), 256, 0, stream>>>(
        nxt + 1024, 2048, W1BT, 1024, HPROJ, 1024, nullptr, 16, 1024, 1024);
    k_attn_e<<<784, 256, 0, stream>>>(PF, HPROJ, attn_w2, EVAL);
    k_attn_fin<0><<<16, 256, 0, stream>>>(EVAL, features, Hst, stop_w, stop_b, nxt, out, s);
  }

  // word chain (batched over 5 sentences; double-buffered h)
  unsigned short* HW[2] = {HW0, HW1};
  for (int w = 0; w < W_; w++){
    k_gemm_cell<16,128,128,2,0><<<dim3(32,5), 128, 0, stream>>>(
        HW[w & 1], 1024, WWHHP, 1024, XW + (size_t)w*80*4096, 4096, w_bih, w_bhh, CW,
        HW[(w + 1) & 1], 1024, HBALL + (size_t)w*80*1024, nullptr, 80, 1024);
  }

  // fc: preds = Hball @ fc_w + fc_b, scattered (nt). Grid padded to 120 n-blocks
  // so bid%8 == by%8: all 8 M-blocks of a B-slice share one XCD's L2.
  k_gemm<128,128,64,2,2,2><<<dim3(120,8), 256, 0, stream>>>(HBALL,1024, FCWT,1024, out,V_, fc_b, 960,15000,1024);
}